// Round 10
// baseline (198.379 us; speedup 1.0000x reference)
//
#include <hip/hip_runtime.h>
#include <stdint.h>

// lap = I - adj/k, adj = exact k-NN graph (incl. self) under euclidean
// distance with jax.lax.top_k tie-break (lower index wins).
//
// Structure (lessons R2..R8):
//   - prep kernel packs (-2x,-2y,-2z,|p|^2) -> d_ws. rn(-2b*a) = -2*rn(a*b)
//     exactly, so d2 = rn(rn(sqi+sqj) + dot_m2) is bitwise-identical to the
//     reference rn(rn(sqi+sqj) - rn(2*rn(dot))). (validated R7/R8, absmax 0)
//   - main kernel: 1 wave/row, 8 rows/block; candidates from a 64 KB LDS tile.
//   - __launch_bounds__(512, 4): the 2nd arg is honored as waves/EU target;
//     (512,2) capped the kernel at 1 block/CU (R6/R8 occ ~19%) while (512,4)
//     gives 2 blocks/CU (R3/R4 occ ~38-40%). THE fix this round.
//   - pass1: per-lane sorted top-5 distances (fmin/med3, NO indices -> no
//     spill; index tracking spilled 3.4 GB in R5).
//   - ballot binary search over float-bit space for D = kth smallest.
//   - pass2: recompute d2 (bitwise-identical), per-lane selmask (d < D),
//     64-ballot bit-transpose -> per-lane register wmask (no LDS bitmask,
//     no atomics); lowest-j rounds for the == D remainder.
//   - Exact: if any lane's 5th-smallest <= D the bsearch counts could be
//     stale -> serial wave-min fallback (P ~ 7e-4/row).

constexpr int Npts = 4096;
constexpr int BLK  = 512;   // 8 waves = 8 rows per block

typedef unsigned long long u64;

__device__ inline u64 u64min(u64 a, u64 b) { return a < b ? a : b; }

__device__ inline u64 wave_min64(u64 v) {
#pragma unroll
    for (int off = 1; off < 64; off <<= 1) {
        u64 o = __shfl_xor(v, off, 64);
        v = u64min(v, o);
    }
    return v;
}

__device__ inline unsigned wave_min32(unsigned v) {
#pragma unroll
    for (int off = 1; off < 64; off <<= 1) {
        unsigned o = __shfl_xor(v, off, 64);
        v = v < o ? v : o;
    }
    return v;
}

__device__ inline unsigned wave_max32(unsigned v) {
#pragma unroll
    for (int off = 1; off < 64; off <<= 1) {
        unsigned o = __shfl_xor(v, off, 64);
        v = v > o ? v : o;
    }
    return v;
}

// d2 from packed (m2x=-2x, m2y=-2y, m2z=-2z, sq); bitwise == reference.
__device__ inline float cand_d2(const float4 pj, float ax, float ay, float az,
                                float sqi) {
    const float u = __fadd_rn(__fadd_rn(__fmul_rn(pj.x, ax), __fmul_rn(pj.y, ay)),
                              __fmul_rn(pj.z, az));        // == -2*rn_dot exactly
    const float v = __fadd_rn(__fadd_rn(sqi, pj.w), u);    // rn(rn(si+sj)-2t)
    return fmaxf(v, 0.0f);   // >= +0.0 -> u32 bit order == float order
}

__global__ __launch_bounds__(256) void prep_kernel(const float* __restrict__ x,
                                                   float4* __restrict__ p,
                                                   int total) {
    const int t = blockIdx.x * 256 + threadIdx.x;
    if (t >= total) return;
    const float bx = x[3 * t], by = x[3 * t + 1], bz = x[3 * t + 2];
    const float sq = __fadd_rn(__fadd_rn(__fmul_rn(bx, bx), __fmul_rn(by, by)),
                               __fmul_rn(bz, bz));
    p[t] = make_float4(-2.0f * bx, -2.0f * by, -2.0f * bz, sq);  // *2 exact
}

__global__ __launch_bounds__(BLK, 4) void gcn_lap_kernel(const float* __restrict__ x,
                                                         const float4* __restrict__ pts,
                                                         const int* __restrict__ kptr,
                                                         float* __restrict__ out) {
    __shared__ float4 pts4[Npts];   // EXACTLY 64 KB -> 2 blocks/CU

    const int tid  = threadIdx.x;
    const int lane = tid & 63;
    const int wv   = tid >> 6;
    const int b    = blockIdx.x >> 9;                  // 512 blocks per batch
    const int i    = ((blockIdx.x & 511) << 3) | wv;   // this wave's row (0..4095)

    int k = *kptr;
    if (k < 1) k = 1;
    if (k > Npts) k = Npts;

    // ---- stage packed points once per block (pure float4 copy) ----
    const float4* pb = pts + (size_t)b * Npts;
#pragma unroll
    for (int s = 0; s < Npts / BLK; ++s)
        pts4[tid + BLK * s] = pb[tid + BLK * s];
    __syncthreads();

    const float* xb = x + (size_t)b * (Npts * 3);
    const float ax = xb[3 * i], ay = xb[3 * i + 1], az = xb[3 * i + 2];
    const float sqi = pts4[i].w;               // wave-uniform broadcast read
    const float INF_F = __uint_as_float(0x7f800000u);

    // ---- pass1: per-lane sorted top-5 distances (no indices) ----
    float d0 = INF_F, d1 = INF_F, d2v = INF_F, d3 = INF_F, d4 = INF_F;
#pragma unroll 8
    for (unsigned c = 0; c < 64; ++c) {
        const float d = cand_d2(pts4[(c << 6) | (unsigned)lane], ax, ay, az, sqi);
        const float n4 = __builtin_amdgcn_fmed3f(d3, d4, d);  // all read OLD values
        const float n3 = __builtin_amdgcn_fmed3f(d2v, d3, d);
        const float n2 = __builtin_amdgcn_fmed3f(d1, d2v, d);
        const float n1 = __builtin_amdgcn_fmed3f(d0, d1, d);
        const float n0 = fminf(d0, d);
        d0 = n0; d1 = n1; d2v = n2; d3 = n3; d4 = n4;
    }
    const unsigned db0 = __float_as_uint(d0), db1 = __float_as_uint(d1),
                   db2 = __float_as_uint(d2v), db3 = __float_as_uint(d3),
                   db4 = __float_as_uint(d4);

    // ---- ballot binary search for D = bits of the kth smallest ----
    // k <= 64: all 64 lane-minima < wave_max(db0)+1 -> count(hi) >= 64 >= k.
    unsigned lo = wave_min32(db0);                       // count(< lo) == 0 < k
    unsigned hi = (k <= 64) ? wave_max32(db0) + 1u : 0x7f800001u;
    unsigned n_lt = 0;
    while (hi - lo > 1u) {
        const unsigned mid = (lo + hi) >> 1;
        const unsigned cnt = (unsigned)__popcll(__ballot(db0 < mid)) +
                             (unsigned)__popcll(__ballot(db1 < mid)) +
                             (unsigned)__popcll(__ballot(db2 < mid)) +
                             (unsigned)__popcll(__ballot(db3 < mid)) +
                             (unsigned)__popcll(__ballot(db4 < mid));
        if (cnt < (unsigned)k) { lo = mid; n_lt = cnt; } else { hi = mid; }
    }
    // exact unless a lane's cache might hide entries <= D
    const bool bad = (__any(db4 <= lo) != 0) || (k > 256);

    u64 wmask = 0;   // per-lane output bits: bit (q*4+e) = element (q<<8)|(lane<<2)|e

    if (!bad) {
        // ---- pass2: recompute, build per-lane selection masks ----
        u64 selmask = 0, eqmask = 0;
#pragma unroll 8
        for (unsigned c = 0; c < 64; ++c) {
            const float d = cand_d2(pts4[(c << 6) | (unsigned)lane], ax, ay, az, sqi);
            const unsigned dbits = __float_as_uint(d);
            selmask |= (u64)(dbits < lo) << c;
            eqmask  |= (u64)(dbits == lo) << c;
        }
        // ---- 64-ballot bit transpose: selmask (by candidate) -> wmask (by owner)
        // candidate j = c*64+l  <->  owner o = (j>>2)&63, bit ((j>>8)<<2)|(j&3).
        // For owner o: bit (q*4+e) comes from ballot of c = 4q+(o>>4), lane
        // l = 4*(o&15)+e  -> nibble (B >> 4*(o&15)) at position 4q.
        const unsigned csel  = (unsigned)lane >> 4;        // which c&3 this lane uses
        const unsigned nibsh = ((unsigned)lane & 15u) << 2;
#pragma unroll
        for (unsigned cc = 0; cc < 64; ++cc) {
            const u64 B = __ballot((selmask >> cc) & 1ull);
            if ((cc & 3u) == csel)
                wmask |= (u64)((B >> nibsh) & 0xFull) << ((cc >> 2) << 2);
        }
        // ---- pick (k - n_lt) lowest-j entries among dist == D (typ. 1 round) ----
        int rem = k - (int)n_lt;
        while (rem > 0) {
            const unsigned myj = eqmask
                ? (((unsigned)(__ffsll((long long)eqmask) - 1) << 6) | (unsigned)lane)
                : 0xFFFFFFFFu;
            const unsigned mn = wave_min32(myj);
            if (mn == 0xFFFFFFFFu) break;    // safety (cannot happen when !bad)
            if (((mn >> 2) & 63u) == (unsigned)lane)       // owner lane marks it
                wmask |= 1ull << (((mn >> 8) << 2) | (mn & 3u));
            if (myj == mn) eqmask &= eqmask - 1;           // winner pops its bit
            --rem;
        }
    } else {
        // ---- exact serial fallback: k rounds of wave-min over rescans ----
        u64 used = 0;
        for (int t = 0; t < k; ++t) {
            u64 best = ~0ull;
            for (unsigned c = 0; c < 64; ++c) {
                if (!((used >> c) & 1ull)) {
                    const unsigned j = (c << 6) | (unsigned)lane;
                    const float d = cand_d2(pts4[j], ax, ay, az, sqi);
                    best = u64min(best, ((u64)__float_as_uint(d) << 32) | j);
                }
            }
            const u64 m = wave_min64(best);
            if (m == ~0ull) break;
            const unsigned j = (unsigned)m;                // winner j, wave-uniform
            if (((j >> 2) & 63u) == (unsigned)lane)        // owner lane marks it
                wmask |= 1ull << (((j >> 8) << 2) | (j & 3u));
            if (best == m) used |= 1ull << (j >> 6);       // unique -> one winner
        }
    }

    // ---- emit row from register wmask: coalesced float4 stream ----
    const float r = 1.0f / sqrtf((float)k);
    const float negrr = -__fmul_rn(r, r);    // -(dinv_i*dinv_j); deg == k exactly
    float4* o4 = (float4*)(out + (size_t)(b * Npts + i) * Npts);
    const int qi = i >> 8;                   // uniform: q holding the diagonal
#pragma unroll
    for (int q = 0; q < 16; ++q) {
        float4 v;
        v.x = ((wmask >> (q * 4 + 0)) & 1ull) ? negrr : 0.0f;
        v.y = ((wmask >> (q * 4 + 1)) & 1ull) ? negrr : 0.0f;
        v.z = ((wmask >> (q * 4 + 2)) & 1ull) ? negrr : 0.0f;
        v.w = ((wmask >> (q * 4 + 3)) & 1ull) ? negrr : 0.0f;
        if (q == qi) {                       // uniform branch: diag lives here
            const int j0 = (q << 8) | (lane << 2);
            v.x = __fadd_rn(v.x, (j0 + 0 == i) ? 1.0f : 0.0f);
            v.y = __fadd_rn(v.y, (j0 + 1 == i) ? 1.0f : 0.0f);
            v.z = __fadd_rn(v.z, (j0 + 2 == i) ? 1.0f : 0.0f);
            v.w = __fadd_rn(v.w, (j0 + 3 == i) ? 1.0f : 0.0f);
        }
        o4[(q << 6) | lane] = v;
    }
}

extern "C" void kernel_launch(void* const* d_in, const int* in_sizes, int n_in,
                              void* d_out, int out_size, void* d_ws, size_t ws_size,
                              hipStream_t stream) {
    const float* x    = (const float*)d_in[0];
    const int*   kptr = (const int*)d_in[1];
    float*       out  = (float*)d_out;
    float4*      pts  = (float4*)d_ws;               // B*Npts*16 B = 256 KB
    const int total = in_sizes[0] / 3;               // B * Npts points
    const int B     = total / Npts;
    hipLaunchKernelGGL(prep_kernel, dim3((total + 255) / 256), dim3(256), 0, stream,
                       x, pts, total);
    hipLaunchKernelGGL(gcn_lap_kernel, dim3(B * 512), dim3(BLK), 0, stream,
                       x, pts, kptr, out);
}

// Round 11
// 183.971 us; speedup vs baseline: 1.0783x; 1.0783x over previous
//
#include <hip/hip_runtime.h>
#include <stdint.h>

// lap = I - adj/k, adj = exact k-NN graph (incl. self) under euclidean
// distance with jax.lax.top_k tie-break (lower index wins).
//
// Structure (lessons R2..R9):
//   - prep kernel packs (-2x,-2y,-2z,|p|^2) -> d_ws; rn(-2b*a) = -2*rn(a*b)
//     exactly -> d2 = rn(rn(sqi+sqj)+dot_m2) bitwise == reference. (R7/R8/R9)
//   - 1 wave per row; candidates from a 64 KB LDS tile (exactly 64 KB).
//   - BLK=1024 (16 waves/block): R8/R9 ran at only ~8 waves/CU (1 block of
//     512) regardless of launch bounds; a 1024-thread block guarantees >=16
//     waves/CU even at 1 block/CU, and 2 blocks (128KB LDS <= 160KB) = 100%.
//   - pass1: TWO independent sorted-top-5 chains (even/odd candidates) to
//     halve the serial dependence chain; exact bitonic lower-half merge
//     {min(a_i,b_{4-i})} gives the 5 smallest as a multiset (order-agnostic
//     for ballot counting; 5th smallest = max of the five).
//   - ballot binary search for D = kth smallest distance bits.
//   - pass2: recompute d2 (bitwise-identical), selmask/eqmask, 64-ballot
//     bit-transpose into per-lane register wmask; lowest-j rounds for == D.
//   - Exact: if any lane's 5th-smallest <= D -> serial wave-min fallback
//     (P ~ 7e-4 per row).

constexpr int Npts = 4096;
constexpr int BLK  = 1024;   // 16 waves = 16 rows per block

typedef unsigned long long u64;

__device__ inline u64 u64min(u64 a, u64 b) { return a < b ? a : b; }

__device__ inline u64 wave_min64(u64 v) {
#pragma unroll
    for (int off = 1; off < 64; off <<= 1) {
        u64 o = __shfl_xor(v, off, 64);
        v = u64min(v, o);
    }
    return v;
}

__device__ inline unsigned wave_min32(unsigned v) {
#pragma unroll
    for (int off = 1; off < 64; off <<= 1) {
        unsigned o = __shfl_xor(v, off, 64);
        v = v < o ? v : o;
    }
    return v;
}

__device__ inline unsigned wave_max32(unsigned v) {
#pragma unroll
    for (int off = 1; off < 64; off <<= 1) {
        unsigned o = __shfl_xor(v, off, 64);
        v = v > o ? v : o;
    }
    return v;
}

// d2 from packed (m2x=-2x, m2y=-2y, m2z=-2z, sq); bitwise == reference.
__device__ inline float cand_d2(const float4 pj, float ax, float ay, float az,
                                float sqi) {
    const float u = __fadd_rn(__fadd_rn(__fmul_rn(pj.x, ax), __fmul_rn(pj.y, ay)),
                              __fmul_rn(pj.z, az));        // == -2*rn_dot exactly
    const float v = __fadd_rn(__fadd_rn(sqi, pj.w), u);    // rn(rn(si+sj)-2t)
    return fmaxf(v, 0.0f);   // >= +0.0 -> u32 bit order == float order
}

// branchless sorted insert of d into ascending quintuple (all read OLD values)
#define INSERT5(q0, q1, q2, q3, q4, d)                                  \
    {                                                                   \
        const float n4 = __builtin_amdgcn_fmed3f(q3, q4, d);            \
        const float n3 = __builtin_amdgcn_fmed3f(q2, q3, d);            \
        const float n2 = __builtin_amdgcn_fmed3f(q1, q2, d);            \
        const float n1 = __builtin_amdgcn_fmed3f(q0, q1, d);            \
        const float n0 = fminf(q0, d);                                  \
        q0 = n0; q1 = n1; q2 = n2; q3 = n3; q4 = n4;                    \
    }

__global__ __launch_bounds__(256) void prep_kernel(const float* __restrict__ x,
                                                   float4* __restrict__ p,
                                                   int total) {
    const int t = blockIdx.x * 256 + threadIdx.x;
    if (t >= total) return;
    const float bx = x[3 * t], by = x[3 * t + 1], bz = x[3 * t + 2];
    const float sq = __fadd_rn(__fadd_rn(__fmul_rn(bx, bx), __fmul_rn(by, by)),
                               __fmul_rn(bz, bz));
    p[t] = make_float4(-2.0f * bx, -2.0f * by, -2.0f * bz, sq);  // *2 exact
}

__global__ __launch_bounds__(BLK, 8) void gcn_lap_kernel(const float* __restrict__ x,
                                                         const float4* __restrict__ pts,
                                                         const int* __restrict__ kptr,
                                                         float* __restrict__ out) {
    __shared__ float4 pts4[Npts];   // EXACTLY 64 KB

    const int tid  = threadIdx.x;
    const int lane = tid & 63;
    const int wv   = tid >> 6;                         // 0..15
    const int b    = blockIdx.x >> 8;                  // 256 blocks per batch
    const int i    = ((blockIdx.x & 255) << 4) | wv;   // this wave's row (0..4095)

    int k = *kptr;
    if (k < 1) k = 1;
    if (k > Npts) k = Npts;

    // ---- stage packed points once per block (pure float4 copy) ----
    const float4* pb = pts + (size_t)b * Npts;
#pragma unroll
    for (int s = 0; s < Npts / BLK; ++s)
        pts4[tid + BLK * s] = pb[tid + BLK * s];
    __syncthreads();

    const float* xb = x + (size_t)b * (Npts * 3);
    const float ax = xb[3 * i], ay = xb[3 * i + 1], az = xb[3 * i + 2];
    const float sqi = pts4[i].w;               // wave-uniform broadcast read
    const float INF_F = __uint_as_float(0x7f800000u);

    // ---- pass1: two independent sorted-top-5 chains (even / odd c) ----
    float a0 = INF_F, a1 = INF_F, a2 = INF_F, a3 = INF_F, a4 = INF_F;
    float f0 = INF_F, f1 = INF_F, f2 = INF_F, f3 = INF_F, f4 = INF_F;
#pragma unroll 4
    for (unsigned c = 0; c < 64; c += 2) {
        const float dA = cand_d2(pts4[(c << 6) | (unsigned)lane], ax, ay, az, sqi);
        const float dB = cand_d2(pts4[((c + 1) << 6) | (unsigned)lane], ax, ay, az, sqi);
        INSERT5(a0, a1, a2, a3, a4, dA);
        INSERT5(f0, f1, f2, f3, f4, dB);
    }
    // exact bitonic lower-half merge: 5 smallest of the union (multiset)
    const float e0 = fminf(a0, f4), e1 = fminf(a1, f3), e2 = fminf(a2, f2),
                e3 = fminf(a3, f1), e4 = fminf(a4, f0);
    const float fifth = fmaxf(fmaxf(fmaxf(e0, e1), fmaxf(e2, e3)), e4);
    const unsigned eb0 = __float_as_uint(e0), eb1 = __float_as_uint(e1),
                   eb2 = __float_as_uint(e2), eb3 = __float_as_uint(e3),
                   eb4 = __float_as_uint(e4);
    const unsigned mylo = __float_as_uint(fminf(a0, f0));   // lane's true min

    // ---- ballot binary search for D = bits of the kth smallest ----
    // k <= 64: all 64 lane-minima < wave_max(mylo)+1 -> count(hi) >= 64 >= k.
    unsigned lo = wave_min32(mylo);                      // count(< lo) == 0 < k
    unsigned hi = (k <= 64) ? wave_max32(mylo) + 1u : 0x7f800001u;
    unsigned n_lt = 0;
    while (hi - lo > 1u) {
        const unsigned mid = (lo + hi) >> 1;
        const unsigned cnt = (unsigned)__popcll(__ballot(eb0 < mid)) +
                             (unsigned)__popcll(__ballot(eb1 < mid)) +
                             (unsigned)__popcll(__ballot(eb2 < mid)) +
                             (unsigned)__popcll(__ballot(eb3 < mid)) +
                             (unsigned)__popcll(__ballot(eb4 < mid));
        if (cnt < (unsigned)k) { lo = mid; n_lt = cnt; } else { hi = mid; }
    }
    // exact unless a lane's cache might hide entries <= D
    const bool bad = (__any(__float_as_uint(fifth) <= lo) != 0) || (k > 256);

    u64 wmask = 0;   // per-lane output bits: bit (q*4+e) = element (q<<8)|(lane<<2)|e

    if (!bad) {
        // ---- pass2: recompute, build per-lane selection masks ----
        u64 selmask = 0, eqmask = 0;
#pragma unroll 8
        for (unsigned c = 0; c < 64; ++c) {
            const float d = cand_d2(pts4[(c << 6) | (unsigned)lane], ax, ay, az, sqi);
            const unsigned dbits = __float_as_uint(d);
            selmask |= (u64)(dbits < lo) << c;
            eqmask  |= (u64)(dbits == lo) << c;
        }
        // ---- 64-ballot bit transpose: selmask (by candidate) -> wmask (by owner)
        // candidate j = c*64+l <-> owner o = (j>>2)&63, bit ((j>>8)<<2)|(j&3).
        const unsigned csel  = (unsigned)lane >> 4;        // which c&3 this lane uses
        const unsigned nibsh = ((unsigned)lane & 15u) << 2;
#pragma unroll
        for (unsigned cc = 0; cc < 64; ++cc) {
            const u64 B = __ballot((selmask >> cc) & 1ull);
            if ((cc & 3u) == csel)
                wmask |= (u64)((B >> nibsh) & 0xFull) << ((cc >> 2) << 2);
        }
        // ---- pick (k - n_lt) lowest-j entries among dist == D (typ. 1 round) ----
        int rem = k - (int)n_lt;
        while (rem > 0) {
            const unsigned myj = eqmask
                ? (((unsigned)(__ffsll((long long)eqmask) - 1) << 6) | (unsigned)lane)
                : 0xFFFFFFFFu;
            const unsigned mn = wave_min32(myj);
            if (mn == 0xFFFFFFFFu) break;    // safety (cannot happen when !bad)
            if (((mn >> 2) & 63u) == (unsigned)lane)       // owner lane marks it
                wmask |= 1ull << (((mn >> 8) << 2) | (mn & 3u));
            if (myj == mn) eqmask &= eqmask - 1;           // winner pops its bit
            --rem;
        }
    } else {
        // ---- exact serial fallback: k rounds of wave-min over rescans ----
        u64 used = 0;
        for (int t = 0; t < k; ++t) {
            u64 best = ~0ull;
            for (unsigned c = 0; c < 64; ++c) {
                if (!((used >> c) & 1ull)) {
                    const unsigned j = (c << 6) | (unsigned)lane;
                    const float d = cand_d2(pts4[j], ax, ay, az, sqi);
                    best = u64min(best, ((u64)__float_as_uint(d) << 32) | j);
                }
            }
            const u64 m = wave_min64(best);
            if (m == ~0ull) break;
            const unsigned j = (unsigned)m;                // winner j, wave-uniform
            if (((j >> 2) & 63u) == (unsigned)lane)        // owner lane marks it
                wmask |= 1ull << (((j >> 8) << 2) | (j & 3u));
            if (best == m) used |= 1ull << (j >> 6);       // unique -> one winner
        }
    }

    // ---- emit row from register wmask: coalesced float4 stream ----
    const float r = 1.0f / sqrtf((float)k);
    const float negrr = -__fmul_rn(r, r);    // -(dinv_i*dinv_j); deg == k exactly
    float4* o4 = (float4*)(out + (size_t)(b * Npts + i) * Npts);
    const int qi = i >> 8;                   // uniform: q holding the diagonal
#pragma unroll
    for (int q = 0; q < 16; ++q) {
        float4 v;
        v.x = ((wmask >> (q * 4 + 0)) & 1ull) ? negrr : 0.0f;
        v.y = ((wmask >> (q * 4 + 1)) & 1ull) ? negrr : 0.0f;
        v.z = ((wmask >> (q * 4 + 2)) & 1ull) ? negrr : 0.0f;
        v.w = ((wmask >> (q * 4 + 3)) & 1ull) ? negrr : 0.0f;
        if (q == qi) {                       // uniform branch: diag lives here
            const int j0 = (q << 8) | (lane << 2);
            v.x = __fadd_rn(v.x, (j0 + 0 == i) ? 1.0f : 0.0f);
            v.y = __fadd_rn(v.y, (j0 + 1 == i) ? 1.0f : 0.0f);
            v.z = __fadd_rn(v.z, (j0 + 2 == i) ? 1.0f : 0.0f);
            v.w = __fadd_rn(v.w, (j0 + 3 == i) ? 1.0f : 0.0f);
        }
        o4[(q << 6) | lane] = v;
    }
}

extern "C" void kernel_launch(void* const* d_in, const int* in_sizes, int n_in,
                              void* d_out, int out_size, void* d_ws, size_t ws_size,
                              hipStream_t stream) {
    const float* x    = (const float*)d_in[0];
    const int*   kptr = (const int*)d_in[1];
    float*       out  = (float*)d_out;
    float4*      pts  = (float4*)d_ws;               // B*Npts*16 B = 256 KB
    const int total = in_sizes[0] / 3;               // B * Npts points
    const int B     = total / Npts;
    hipLaunchKernelGGL(prep_kernel, dim3((total + 255) / 256), dim3(256), 0, stream,
                       x, pts, total);
    hipLaunchKernelGGL(gcn_lap_kernel, dim3(B * (Npts / (BLK / 64))), dim3(BLK), 0,
                       stream, x, pts, kptr, out);
}